// Round 6
// baseline (1826.387 us; speedup 1.0000x reference)
//
#include <hip/hip_runtime.h>
#include <hip/hip_bf16.h>
#include <math.h>

#define Bn 128
#define Sn 512
#define Tn 256

typedef unsigned int vu16t __attribute__((ext_vector_type(16)));
typedef _Float16 half2_t __attribute__((ext_vector_type(2)));

static __device__ inline float dot2h(unsigned int p, unsigned int e, float acc) {
#if __has_builtin(__builtin_amdgcn_fdot2)
    return __builtin_amdgcn_fdot2(__builtin_bit_cast(half2_t, p),
                                  __builtin_bit_cast(half2_t, e), acc, false);
#else
    half2_t ph = __builtin_bit_cast(half2_t, p), eh = __builtin_bit_cast(half2_t, e);
    return acc + (float)ph.x * (float)eh.x + (float)ph.y * (float)eh.y;
#endif
}

// ===================================================================
// FAST PATH
// ===================================================================

// E16 = exp(trans) f16 packed by row-pairs (word w = r2*256+c holds rows {2r2,2r2+1});
// per-block min/max of trans -> rngmin/rngmax[256]
__global__ void prep_kernel(const float* __restrict__ trans, _Float16* __restrict__ E16,
                            float* __restrict__ rngmin, float* __restrict__ rngmax) {
    int blk = blockIdx.x, tid = threadIdx.x;       // 256 blocks x 256 threads
    int k = blk * 256 + tid;
    int i = k >> 8, c = k & 255;
    float v = trans[k];
    E16[(size_t)(i >> 1) * 512 + c * 2 + (i & 1)] = (_Float16)__expf(v);
    float mn = v, mx = v;
    #pragma unroll
    for (int off = 32; off; off >>= 1) {
        mn = fminf(mn, __shfl_xor(mn, off));
        mx = fmaxf(mx, __shfl_xor(mx, off));
    }
    __shared__ float smn[4], smx[4];
    if ((tid & 63) == 0) { smn[tid >> 6] = mn; smx[tid >> 6] = mx; }
    __syncthreads();
    if (tid == 0) {
        rngmin[blk] = fminf(fminf(smn[0], smn[1]), fminf(smn[2], smn[3]));
        rngmax[blk] = fmaxf(fmaxf(smx[0], smx[1]), fmaxf(smx[2], smx[3]));
    }
}

__global__ void range_kernel(const float* __restrict__ rngmin, const float* __restrict__ rngmax,
                             float* __restrict__ Rout) {
    int tid = threadIdx.x;                          // 256 threads
    float mn = rngmin[tid], mx = rngmax[tid];
    #pragma unroll
    for (int off = 32; off; off >>= 1) {
        mn = fminf(mn, __shfl_xor(mn, off));
        mx = fmaxf(mx, __shfl_xor(mx, off));
    }
    __shared__ float smn[4], smx[4];
    if ((tid & 63) == 0) { smn[tid >> 6] = mn; smx[tid >> 6] = mx; }
    __syncthreads();
    if (tid == 0) {
        float MN = fminf(fminf(smn[0], smn[1]), fminf(smn[2], smn[3]));
        float MX = fmaxf(fmaxf(smx[0], smx[1]), fmaxf(smx[2], smx[3]));
        Rout[0] = (MX - MN) * 1.000001f + 1e-6f;    // slight over-bound: safe (more candidates)
    }
}

// blocks 0..127: pruned Viterbi + fused byte backtrack (batch b).
// blocks 128..255: denominator (f16 dot2, reg-resident E16) + numerator.
__launch_bounds__(512, 2)
__global__ void crf_fwd5_kernel(const float* __restrict__ logits,
                                const float* __restrict__ start_t,
                                const float* __restrict__ end_t,
                                const float* __restrict__ trans,
                                const unsigned int* __restrict__ E16w,
                                const void* __restrict__ mask,
                                const int* __restrict__ labels,
                                const float* __restrict__ Rptr,
                                unsigned char* __restrict__ hist8,   // [S][B][T] argmax bytes
                                float* __restrict__ den_out,
                                float* __restrict__ num_out,
                                float* __restrict__ pred) {
    const int bid = blockIdx.x;
    const bool is_vit = bid < Bn;
    const int b = is_vit ? bid : bid - Bn;
    const int tid = threadIdx.x;
    const int wv = tid >> 6, lane = tid & 63;

    __shared__ __align__(16) float sbuf[Tn];       // vit state (for rare full-scan fallback)
    __shared__ __align__(16) _Float16 p16[Tn];     // den p
    __shared__ __align__(16) float part[8 * Tn];   // den partials
    __shared__ float candv[64];
    __shared__ int   cand[64];
    __shared__ int   ccnt[8];
    __shared__ float msh[2];
    __shared__ float wredf[8];
    __shared__ int   wredi[8];
    __shared__ float wnum[8];
    __shared__ int   lenred[8];
    __shared__ int   tg[Sn];
    __shared__ int   lastSh;

    // ---- length from mask (512 threads cover Sn) ----
    int nz;
    {
        const unsigned int* mu = (const unsigned int*)mask;
        unsigned int w0 = mu[0];
        if (w0 == 1u)                nz = (((const int*)mask)[b * Sn + tid] != 0);
        else if (w0 == 0x3F800000u)  nz = (((const float*)mask)[b * Sn + tid] != 0.0f);
        else                         nz = (((const unsigned char*)mask)[b * Sn + tid] != 0);
    }
    unsigned long long bal0 = __ballot(nz != 0);
    if (lane == 0) lenred[wv] = __popcll(bal0);
    __syncthreads();
    int len = 0;
    #pragma unroll
    for (int w = 0; w < 8; ++w) len += lenred[w];

    if (is_vit) {
        // ================= pruned Viterbi =================
        const int j = tid & 255;                    // column (tid>=256 duplicates compute)
        const float R = Rptr[0];
        const float* lg = logits + (size_t)b * Sn * Tn + j;

        float cur = start_t[j] + lg[0];
        float emit_cur = lg[Tn];
        float emit_next = 0.0f;
        if (tid < Tn) sbuf[j] = cur;

        for (int t = 1; t < len; ++t) {
            {
                int tn = (t + 1 < len) ? (t + 1) : (len - 1);
                emit_next = lg[(size_t)tn * Tn];
            }
            // wave-local max threshold (superset of exact candidate set -> still exact)
            float wm = cur;
            #pragma unroll
            for (int off = 32; off; off >>= 1) wm = fmaxf(wm, __shfl_xor(wm, off));
            int flag = (cur >= wm - R) ? 1 : 0;
            unsigned long long bal = __ballot(flag);
            if (lane == 0) ccnt[wv] = __popcll(bal);
            __syncthreads();                                   // B
            int K = ccnt[0] + ccnt[1] + ccnt[2] + ccnt[3];
            if (tid < Tn && flag && K <= 64) {
                int base = 0;
                #pragma unroll
                for (int w = 0; w < 4; ++w) if (w < wv) base += ccnt[w];
                int rank = base + __popcll(bal & (((unsigned long long)1 << lane) - 1));
                cand[rank] = j;
                candv[rank] = cur;
            }
            __syncthreads();                                   // C

            float best = -INFINITY; int arg = 0;
            if (K <= 64) {
                for (int k0 = 0; k0 < K; k0 += 16) {
                    float tv[16];
                    #pragma unroll
                    for (int u = 0; u < 16; ++u)
                        if (k0 + u < K) tv[u] = trans[(size_t)cand[k0 + u] * Tn + j];
                    #pragma unroll
                    for (int u = 0; u < 16; ++u)
                        if (k0 + u < K) {
                            float c = candv[k0 + u] + tv[u];
                            if (c > best) { best = c; arg = cand[k0 + u]; }
                        }
                }
            } else {
                // full scan fallback (never expected with random inputs)
                for (int k0 = 0; k0 < Tn; k0 += 16) {
                    float tv[16], cv[16];
                    #pragma unroll
                    for (int u = 0; u < 16; ++u) {
                        tv[u] = trans[(size_t)(k0 + u) * Tn + j];
                        cv[u] = sbuf[k0 + u];
                    }
                    #pragma unroll
                    for (int u = 0; u < 16; ++u) {
                        float c = cv[u] + tv[u];
                        if (c > best) { best = c; arg = k0 + u; }
                    }
                }
            }
            if (tid < Tn) hist8[((size_t)t * Bn + b) * Tn + j] = (unsigned char)arg;
            cur = best + emit_cur;
            emit_cur = emit_next;
            if (tid < Tn) sbuf[j] = cur;
        }

        // ---- last = argmax_j(cur + end_t[j]), ties -> smallest j ----
        float bv = (tid < Tn) ? (cur + end_t[j]) : -INFINITY;
        int bj = (tid < Tn) ? j : 0;
        #pragma unroll
        for (int off = 32; off; off >>= 1) {
            float ov = __shfl_xor(bv, off);
            int   oj = __shfl_xor(bj, off);
            if (ov > bv || (ov == bv && oj < bj)) { bv = ov; bj = oj; }
        }
        if (lane == 0) { wredf[wv] = bv; wredi[wv] = bj; }
        __syncthreads();
        if (tid == 0) {
            float BB = wredf[0]; int AA = wredi[0];
            #pragma unroll
            for (int w = 1; w < 4; ++w)
                if (wredf[w] > BB || (wredf[w] == BB && wredi[w] < AA)) { BB = wredf[w]; AA = wredi[w]; }
            lastSh = AA;
        }
        __syncthreads();
        __threadfence();   // make this block's hist8 stores visible to its own reads

        // ---- byte-chase backtrack (wave 0 only; rows L2-hot) ----
        if (wv == 0) {
            int len1 = len - 1;
            int tag = lastSh;
            const int P = 16;
            unsigned int buf[P];
            #pragma unroll
            for (int q = 0; q < P; ++q) {
                int r = len1 - q;
                if (q < len1)
                    buf[q] = *(const unsigned int*)(hist8 + ((size_t)r * Bn + b) * Tn + lane * 4);
            }
            if (lane == 0) tg[len1] = tag;
            for (int q = 0; q < len1; ++q) {
                unsigned int w = buf[q & (P - 1)];
                int sel = __shfl((int)w, tag >> 2, 64);
                tag = (sel >> ((tag & 3) * 8)) & 255;
                if (lane == 0) tg[len1 - 1 - q] = tag;
                int rn = len1 - q - P;
                if (rn >= 1)
                    buf[q & (P - 1)] = *(const unsigned int*)(hist8 + ((size_t)rn * Bn + b) * Tn + lane * 4);
            }
        }
        __syncthreads();
        pred[(size_t)b * Sn + tid] = (tid < len) ? (float)tg[tid] : 0.0f;
    } else {
        // ================= denominator (proven fwd3 structure) =================
        const int jp = tid & 63;
        const int q  = tid >> 6;          // row-group 0..7 (32 rows each)
        const int j0 = jp * 4;
        const float* lg = logits + (size_t)b * Sn * Tn + tid;   // tid<256 use
        const unsigned int* p16w = (const unsigned int*)p16;

        vu16t tdA, tdB, tdC, tdD;
        #pragma unroll
        for (int k = 0; k < 16; ++k) {
            uint4 v = *(const uint4*)(E16w + (size_t)(16 * q + k) * Tn + j0);
            tdA[k] = v.x; tdB[k] = v.y; tdC[k] = v.z; tdD[k] = v.w;
        }

        const float SHIFT = 9.0f;
        float cur = 0.0f, emit_cur = 0.0f, emit_next = 0.0f, pbase = 0.0f;
        if (tid < Tn) {
            cur = start_t[tid] + lg[0];
            if (tid == 0) msh[0] = cur;
            emit_cur = lg[Tn];
        }
        __syncthreads();
        if (tid < Tn) {
            pbase = msh[0] + SHIFT;
            p16[tid] = (_Float16)__expf(cur - pbase);
        }
        __syncthreads();

        for (int t = 1; t < len; ++t) {
            if (tid < Tn) {
                int tn = (t + 1 < len) ? (t + 1) : (len - 1);
                emit_next = lg[(size_t)tn * Tn];
            }
            float sA = 0.f, sB = 0.f, sC = 0.f, sD = 0.f;
            #pragma unroll
            for (int k = 0; k < 8; ++k) {
                uint2 pp = *(const uint2*)(p16w + q * 16 + 2 * k);
                int i = 2 * k;
                sA = dot2h(pp.x, tdA[i], sA); sA = dot2h(pp.y, tdA[i + 1], sA);
                sB = dot2h(pp.x, tdB[i], sB); sB = dot2h(pp.y, tdB[i + 1], sB);
                sC = dot2h(pp.x, tdC[i], sC); sC = dot2h(pp.y, tdC[i + 1], sC);
                sD = dot2h(pp.x, tdD[i], sD); sD = dot2h(pp.y, tdD[i + 1], sD);
            }
            *(float4*)(part + q * Tn + j0) = make_float4(sA, sB, sC, sD);
            __syncthreads();
            if (tid < Tn) {
                float tot = part[tid];
                #pragma unroll
                for (int q2 = 1; q2 < 8; ++q2) tot += part[q2 * Tn + tid];
                float nb = msh[(t - 1) & 1];
                cur = pbase + __logf(tot) + emit_cur;
                emit_cur = emit_next;
                p16[tid] = (_Float16)__expf(cur - nb - SHIFT);
                pbase = nb + SHIFT;
                if (tid == 0) msh[t & 1] = cur;
            }
            __syncthreads();
        }

        // den = logsumexp_j(cur + end_t[j]) (exact fp32)
        float v2 = (tid < Tn) ? (cur + end_t[tid]) : -INFINITY;
        float wm = v2;
        #pragma unroll
        for (int off = 32; off; off >>= 1) wm = fmaxf(wm, __shfl_xor(wm, off));
        if (lane == 0) wredf[wv] = wm;
        __syncthreads();
        float M = fmaxf(fmaxf(wredf[0], wredf[1]), fmaxf(wredf[2], wredf[3]));
        float ex = (tid < Tn) ? __expf(v2 - M) : 0.0f;
        #pragma unroll
        for (int off = 32; off; off >>= 1) ex += __shfl_xor(ex, off);
        if (lane == 0) wnum[wv] = ex;
        __syncthreads();
        if (tid == 0) den_out[b] = M + __logf(wnum[0] + wnum[1] + wnum[2] + wnum[3]);
        __syncthreads();

        // ---- numerator ----
        float acc = 0.0f;
        if (tid >= 1 && tid < len) {
            int prev = labels[b * Sn + tid - 1], curl = labels[b * Sn + tid];
            acc = trans[prev * Tn + curl] + logits[((size_t)b * Sn + tid) * Tn + curl];
        }
        #pragma unroll
        for (int off = 32; off; off >>= 1) acc += __shfl_xor(acc, off);
        if (lane == 0) wnum[wv] = acc;
        __syncthreads();
        if (tid == 0) {
            float s = 0.0f;
            #pragma unroll
            for (int w = 0; w < 8; ++w) s += wnum[w];
            int l0 = labels[b * Sn];
            int ll = labels[b * Sn + len - 1];
            num_out[b] = start_t[l0] + logits[(size_t)b * Sn * Tn + l0] + s + end_t[ll];
        }
    }
}

// ---------------- loss = mean(den - num) ----------------
__global__ void loss_kernel(const float* __restrict__ num, const float* __restrict__ den,
                            float* __restrict__ out_loss) {
    int tid = threadIdx.x;   // 128 threads
    float v = den[tid] - num[tid];
    for (int off = 32; off; off >>= 1) v += __shfl_xor(v, off);
    __shared__ float r2[2];
    if ((tid & 63) == 0) r2[tid >> 6] = v;
    __syncthreads();
    if (tid == 0) out_loss[0] = (r2[0] + r2[1]) * (1.0f / 128.0f);
}

// ===================================================================
// FALLBACK PATH (round-1, proven): used only if ws_size is too small
// ===================================================================

__global__ void compute_E_kernel(const float* __restrict__ trans, __hip_bfloat16* __restrict__ E) {
    int k = blockIdx.x * blockDim.x + threadIdx.x;
    if (k < Tn * Tn) E[k] = __float2bfloat16(__expf(trans[k]));
}

__global__ void lengths_kernel(const void* __restrict__ mask, int* __restrict__ lengths) {
    int b = blockIdx.x, tid = threadIdx.x;
    const unsigned int* mu = (const unsigned int*)mask;
    unsigned int w0 = mu[0];
    int cnt = 0;
    if (w0 == 1u) {
        const int* mi = (const int*)mask;
        for (int t = tid; t < Sn; t += 256) cnt += (mi[b * Sn + t] != 0);
    } else if (w0 == 0x3F800000u) {
        const float* mf = (const float*)mask;
        for (int t = tid; t < Sn; t += 256) cnt += (mf[b * Sn + t] != 0.0f);
    } else {
        const unsigned char* mb = (const unsigned char*)mask;
        for (int t = tid; t < Sn; t += 256) cnt += (mb[b * Sn + t] != 0);
    }
    for (int off = 32; off; off >>= 1) cnt += __shfl_xor(cnt, off);
    __shared__ int red[4];
    if ((tid & 63) == 0) red[tid >> 6] = cnt;
    __syncthreads();
    if (tid == 0) lengths[b] = red[0] + red[1] + red[2] + red[3];
}

__global__ void numerator_kernel(const float* __restrict__ logits, const int* __restrict__ labels,
                                 const float* __restrict__ start_t, const float* __restrict__ end_t,
                                 const float* __restrict__ trans, const int* __restrict__ lengths,
                                 float* __restrict__ num) {
    int b = blockIdx.x, tid = threadIdx.x;
    int len = lengths[b];
    float acc = 0.0f;
    for (int t = tid + 1; t < len; t += 256) {
        int prev = labels[b * Sn + t - 1], cur = labels[b * Sn + t];
        acc += trans[prev * Tn + cur] + logits[((size_t)b * Sn + t) * Tn + cur];
    }
    for (int off = 32; off; off >>= 1) acc += __shfl_xor(acc, off);
    __shared__ float red[4];
    if ((tid & 63) == 0) red[tid >> 6] = acc;
    __syncthreads();
    if (tid == 0) {
        int l0 = labels[b * Sn];
        int ll = labels[b * Sn + len - 1];
        num[b] = start_t[l0] + logits[(size_t)b * Sn * Tn + l0]
               + red[0] + red[1] + red[2] + red[3] + end_t[ll];
    }
}

__launch_bounds__(1024)
__global__ void fused_fwd_kernel(const float* __restrict__ logits,
                                 const float* __restrict__ start_t,
                                 const float* __restrict__ end_t,
                                 const float* __restrict__ trans,
                                 const __hip_bfloat16* __restrict__ E,
                                 const int* __restrict__ lengths,
                                 unsigned char* __restrict__ hist,
                                 float* __restrict__ den_out,
                                 int* __restrict__ last_out) {
    int b = blockIdx.x;
    int tid = threadIdx.x;
    int j = tid & 255;
    int h = tid >> 8;
    int i0 = h * 64;

    __shared__ __align__(16) float sden[Tn];
    __shared__ __align__(16) float svit[Tn];
    __shared__ __align__(16) float p[Tn];
    __shared__ float redf[16];
    __shared__ float reds[16];
    __shared__ float redb[16];
    __shared__ int   redbi[16];
    __shared__ float pd[1024];
    __shared__ float pv[1024];
    __shared__ int   pa[1024];

    int len = lengths[b];
    if (tid < Tn) {
        float v = start_t[j] + logits[(size_t)b * Sn * Tn + j];
        sden[j] = v;
        svit[j] = v;
    }
    __syncthreads();

    for (int t = 1; t < len; ++t) {
        float v = sden[j];
        for (int off = 32; off; off >>= 1) v = fmaxf(v, __shfl_xor(v, off));
        if ((tid & 63) == 0) redf[tid >> 6] = v;
        __syncthreads();
        float m = redf[0];
        #pragma unroll
        for (int w = 1; w < 16; ++w) m = fmaxf(m, redf[w]);
        if (tid < Tn) p[j] = __expf(sden[j] - m);
        __syncthreads();

        float s = 0.0f, best = -INFINITY;
        int arg = 0;
        const float* tr = trans + (size_t)i0 * Tn + j;
        const __hip_bfloat16* er = E + (size_t)i0 * Tn + j;
        #pragma unroll 4
        for (int i = i0; i < i0 + 64; i += 4) {
            float4 p4  = *(const float4*)(p + i);
            float4 sv4 = *(const float4*)(svit + i);
            float tr0 = tr[0 * Tn], tr1 = tr[1 * Tn], tr2 = tr[2 * Tn], tr3 = tr[3 * Tn];
            float e0 = __bfloat162float(er[0 * Tn]);
            float e1 = __bfloat162float(er[1 * Tn]);
            float e2 = __bfloat162float(er[2 * Tn]);
            float e3 = __bfloat162float(er[3 * Tn]);
            tr += 4 * Tn; er += 4 * Tn;
            s = fmaf(p4.x, e0, s); s = fmaf(p4.y, e1, s);
            s = fmaf(p4.z, e2, s); s = fmaf(p4.w, e3, s);
            float c0 = sv4.x + tr0; if (c0 > best) { best = c0; arg = i + 0; }
            float c1 = sv4.y + tr1; if (c1 > best) { best = c1; arg = i + 1; }
            float c2 = sv4.z + tr2; if (c2 > best) { best = c2; arg = i + 2; }
            float c3 = sv4.w + tr3; if (c3 > best) { best = c3; arg = i + 3; }
        }
        pd[tid] = s; pv[tid] = best; pa[tid] = arg;
        __syncthreads();

        if (tid < Tn) {
            float ss = pd[j] + pd[j + 256] + pd[j + 512] + pd[j + 768];
            float bb = pv[j]; int aa = pa[j];
            if (pv[j + 256] > bb) { bb = pv[j + 256]; aa = pa[j + 256]; }
            if (pv[j + 512] > bb) { bb = pv[j + 512]; aa = pa[j + 512]; }
            if (pv[j + 768] > bb) { bb = pv[j + 768]; aa = pa[j + 768]; }
            float emit = logits[((size_t)b * Sn + t) * Tn + j];
            sden[j] = m + __logf(ss) + emit;
            svit[j] = bb + emit;
            hist[((size_t)t * Bn + b) * Tn + j] = (unsigned char)aa;
        }
        __syncthreads();
    }

    float v2d = sden[j] + end_t[j];
    float M = v2d;
    for (int off = 32; off; off >>= 1) M = fmaxf(M, __shfl_xor(M, off));
    if ((tid & 63) == 0) redf[tid >> 6] = M;
    __syncthreads();
    M = redf[0];
    #pragma unroll
    for (int w = 1; w < 16; ++w) M = fmaxf(M, redf[w]);

    float ex = (tid < Tn) ? __expf(v2d - M) : 0.0f;
    for (int off = 32; off; off >>= 1) ex += __shfl_xor(ex, off);

    float v2v = svit[j] + end_t[j];
    float bv = v2v; int bj = j;
    for (int off = 32; off; off >>= 1) {
        float ov = __shfl_xor(bv, off); int oj = __shfl_xor(bj, off);
        if (ov > bv || (ov == bv && oj < bj)) { bv = ov; bj = oj; }
    }
    if ((tid & 63) == 0) { reds[tid >> 6] = ex; redb[tid >> 6] = bv; redbi[tid >> 6] = bj; }
    __syncthreads();
    if (tid == 0) {
        float sum = 0.0f;
        #pragma unroll
        for (int w = 0; w < 16; ++w) sum += reds[w];
        den_out[b] = M + __logf(sum);
        float BB = redb[0]; int AA = redbi[0];
        #pragma unroll
        for (int w = 1; w < 16; ++w)
            if (redb[w] > BB || (redb[w] == BB && redbi[w] < AA)) { BB = redb[w]; AA = redbi[w]; }
        last_out[b] = AA;
    }
}

__global__ void backtrack_kernel(const unsigned char* __restrict__ hist,
                                 const int* __restrict__ last,
                                 const int* __restrict__ lengths,
                                 float* __restrict__ pred) {
    int b = blockIdx.x, lane = threadIdx.x;
    int len = lengths[b];
    int len1 = len - 1;
    __shared__ int tg[Sn];
    int tag = last[b];

    const int P = 16;
    unsigned int buf[P];
    #pragma unroll
    for (int qq = 0; qq < P; ++qq) {
        int r = len1 - qq;
        if (qq < len1)
            buf[qq] = *(const unsigned int*)(hist + ((size_t)r * Bn + b) * Tn + lane * 4);
    }
    if (lane == 0) tg[len1] = tag;
    for (int qq = 0; qq < len1; ++qq) {
        unsigned int w = buf[qq & (P - 1)];
        int sel = __shfl((int)w, tag >> 2, 64);
        tag = (sel >> ((tag & 3) * 8)) & 255;
        int t = len1 - 1 - qq;
        if (lane == 0) tg[t] = tag;
        int rn = len1 - qq - P;
        if (rn >= 1)
            buf[qq & (P - 1)] = *(const unsigned int*)(hist + ((size_t)rn * Bn + b) * Tn + lane * 4);
    }
    __syncthreads();
    for (int t = lane; t < Sn; t += 64)
        pred[(size_t)b * Sn + t] = (t < len) ? (float)tg[t] : 0.0f;
}

// ===================================================================

extern "C" void kernel_launch(void* const* d_in, const int* in_sizes, int n_in,
                              void* d_out, int out_size, void* d_ws, size_t ws_size,
                              hipStream_t stream) {
    const float* logits  = (const float*)d_in[0];
    const void*  mask    = d_in[1];
    const int*   labels  = (const int*)d_in[2];
    const float* start_t = (const float*)d_in[3];
    const float* end_t   = (const float*)d_in[4];
    const float* trans   = (const float*)d_in[5];
    float* out = (float*)d_out;   // [B*S] pred as float, then [1] loss

    char* ws = (char*)d_ws;
    const size_t hist8Sz = (size_t)Sn * Bn * Tn;             // 16.8 MB uint8 argmax hist
    const size_t e16F    = (size_t)Tn * Tn * 2;              // 128 KB
    const size_t needF   = hist8Sz + e16F + 16384;

    if (ws_size >= needF) {
        // -------- fast path --------
        unsigned char* hist8  = (unsigned char*)ws;
        _Float16*      E16    = (_Float16*)(ws + hist8Sz);
        char*          tail   = ws + hist8Sz + e16F;
        float*         rngmin = (float*)tail;                 // 256 floats
        float*         rngmax = (float*)(tail + 1024);        // 256 floats
        float*         Rout   = (float*)(tail + 2048);
        float*         num    = (float*)(tail + 4096);        // 128 floats
        float*         den    = (float*)(tail + 6144);        // 128 floats

        prep_kernel<<<256, 256, 0, stream>>>(trans, E16, rngmin, rngmax);
        range_kernel<<<1, 256, 0, stream>>>(rngmin, rngmax, Rout);
        crf_fwd5_kernel<<<2 * Bn, 512, 0, stream>>>(logits, start_t, end_t, trans,
                                                    (const unsigned int*)E16, mask, labels,
                                                    Rout, hist8, den, num, out);
        loss_kernel<<<1, 128, 0, stream>>>(num, den, out + (size_t)Bn * Sn);
    } else {
        // -------- fallback: proven round-1 path (~17 MB ws) --------
        const size_t histSz = (size_t)Sn * Bn * Tn;
        unsigned char*  hist    = (unsigned char*)ws;
        int*            lengths = (int*)(ws + histSz);
        float*          num     = (float*)(ws + histSz + 512);
        float*          den     = (float*)(ws + histSz + 1024);
        int*            lastp   = (int*)(ws + histSz + 1536);
        __hip_bfloat16* E       = (__hip_bfloat16*)(ws + histSz + 2048);

        compute_E_kernel<<<(Tn * Tn) / 256, 256, 0, stream>>>(trans, E);
        lengths_kernel<<<Bn, 256, 0, stream>>>(mask, lengths);
        fused_fwd_kernel<<<Bn, 1024, 0, stream>>>(logits, start_t, end_t, trans, E,
                                                  lengths, hist, den, lastp);
        numerator_kernel<<<Bn, 256, 0, stream>>>(logits, labels, start_t, end_t, trans,
                                                 lengths, num);
        backtrack_kernel<<<Bn, 64, 0, stream>>>(hist, lastp, lengths, out);
        loss_kernel<<<1, 128, 0, stream>>>(num, den, out + (size_t)Bn * Sn);
    }
}

// Round 7
// 686.833 us; speedup vs baseline: 2.6591x; 2.6591x over previous
//
#include <hip/hip_runtime.h>
#include <hip/hip_bf16.h>
#include <math.h>

#define Bn 128
#define Sn 512
#define Tn 256

typedef float vf32t __attribute__((ext_vector_type(32)));
typedef unsigned int vu16t __attribute__((ext_vector_type(16)));
typedef _Float16 half2_t __attribute__((ext_vector_type(2)));
typedef float f4v __attribute__((ext_vector_type(4)));

static __device__ inline float dot2h(unsigned int p, unsigned int e, float acc) {
#if __has_builtin(__builtin_amdgcn_fdot2)
    return __builtin_amdgcn_fdot2(__builtin_bit_cast(half2_t, p),
                                  __builtin_bit_cast(half2_t, e), acc, false);
#else
    half2_t ph = __builtin_bit_cast(half2_t, p), eh = __builtin_bit_cast(half2_t, e);
    return acc + (float)ph.x * (float)eh.x + (float)ph.y * (float)eh.y;
#endif
}

// non-temporal 16B load: streaming data that must NOT evict transT from L2
static __device__ inline float4 nt_load4(const float* p) {
    f4v v = __builtin_nontemporal_load((const f4v*)p);
    float4 r; r.x = v.x; r.y = v.y; r.z = v.z; r.w = v.w;
    return r;
}

// ===================================================================
// FAST PATH
// ===================================================================

// transT = trans^T (for backtrack); E16 = exp(trans) as f16, packed by row-pairs:
// word w = r2*256 + c holds rows {2r2, 2r2+1} of column c
__global__ void prep_kernel(const float* __restrict__ trans, float* __restrict__ transT,
                            _Float16* __restrict__ E16) {
    int k = blockIdx.x * blockDim.x + threadIdx.x;   // 65536 threads
    int i = k >> 8, c = k & 255;
    float v = trans[k];
    transT[c * 256 + i] = v;
    E16[((size_t)(i >> 1) * 512) + c * 2 + (i & 1)] = (_Float16)__expf(v);
}

// blocks 0..127: Viterbi fwd (batch b). blocks 128..255: denominator + numerator.
// 512 threads: jp = tid&63 -> 4 cols j0=4jp..4jp+3 ; q = tid>>6 -> rows [32q,32q+32)
__launch_bounds__(512, 2)
__global__ void crf_fwd3_kernel(const float* __restrict__ logits,
                                const float* __restrict__ start_t,
                                const float* __restrict__ end_t,
                                const float* __restrict__ trans,
                                const unsigned int* __restrict__ E16w,
                                const void* __restrict__ mask,
                                const int* __restrict__ labels,
                                int* __restrict__ lengths_out,
                                float* __restrict__ hist,      // [S][B][T] pre-emit best values
                                float* __restrict__ den_out,
                                int* __restrict__ last_out,
                                float* __restrict__ num_out) {
    const int bid = blockIdx.x;
    const bool is_vit = bid < Bn;
    const int b = is_vit ? bid : bid - Bn;
    const int tid = threadIdx.x;
    const int jp = tid & 63;
    const int q  = tid >> 6;          // row-group 0..7
    const int j0 = jp * 4;
    const int i0 = q * 32;
    const int wv = tid >> 6, lane = tid & 63;

    __shared__ __align__(16) float sbuf[Tn];       // state (vit) — f32
    __shared__ __align__(16) _Float16 p16[Tn];     // p (den) — f16
    __shared__ __align__(16) float part[8 * Tn];   // per-(rowgroup,column) partials
    __shared__ float msh[2];
    __shared__ int   lenred[8];
    __shared__ float wredf[8];
    __shared__ int   wredi[8];
    __shared__ float wnum[8];

    // ---- per-block length from mask (dtype auto-detect) ----
    int nz;
    {
        const unsigned int* mu = (const unsigned int*)mask;
        unsigned int w0 = mu[0];
        if (w0 == 1u)                nz = (((const int*)mask)[b * Sn + tid] != 0);
        else if (w0 == 0x3F800000u)  nz = (((const float*)mask)[b * Sn + tid] != 0.0f);
        else                         nz = (((const unsigned char*)mask)[b * Sn + tid] != 0);
    }
    unsigned long long bal = __ballot(nz != 0);
    if (lane == 0) lenred[wv] = __popcll(bal);
    __syncthreads();
    int len = 0;
    #pragma unroll
    for (int w = 0; w < 8; ++w) len += lenred[w];
    if (is_vit && tid == 0) lengths_out[b] = len;

    const float* lg = logits + (size_t)b * Sn * Tn + tid;   // used when tid<256
    const float4* sb4 = (const float4*)sbuf;
    const unsigned int* p16w = (const unsigned int*)p16;

    float cur = 0.0f, emit_cur = 0.0f, emit_next = 0.0f;

    if (is_vit) {
        // ---- register-resident trans columns: 4 cols x 32 rows ----
        vf32t tvA, tvB, tvC, tvD;
        #pragma unroll
        for (int r = 0; r < 32; ++r) {
            float4 v = *(const float4*)(trans + (size_t)(i0 + r) * Tn + j0);
            tvA[r] = v.x; tvB[r] = v.y; tvC[r] = v.z; tvD[r] = v.w;
        }

        if (tid < Tn) {
            cur = start_t[tid] + lg[0];
            sbuf[tid] = cur;
            emit_cur = lg[Tn];
        }
        __syncthreads();

        for (int t = 1; t < len; ++t) {
            if (tid < Tn) {
                int tn = (t + 1 < len) ? (t + 1) : (len - 1);
                emit_next = lg[(size_t)tn * Tn];
            }
            float bA = -INFINITY, bB = -INFINITY, bC = -INFINITY, bD = -INFINITY;
            #pragma unroll
            for (int k = 0; k < 8; ++k) {
                float4 s4 = sb4[q * 8 + k];
                int i = 4 * k;
                float cA0 = s4.x + tvA[i],     cA1 = s4.y + tvA[i + 1];
                float cA2 = s4.z + tvA[i + 2], cA3 = s4.w + tvA[i + 3];
                bA = fmaxf(fmaxf(bA, cA0), cA1); bA = fmaxf(fmaxf(bA, cA2), cA3);
                float cB0 = s4.x + tvB[i],     cB1 = s4.y + tvB[i + 1];
                float cB2 = s4.z + tvB[i + 2], cB3 = s4.w + tvB[i + 3];
                bB = fmaxf(fmaxf(bB, cB0), cB1); bB = fmaxf(fmaxf(bB, cB2), cB3);
                float cC0 = s4.x + tvC[i],     cC1 = s4.y + tvC[i + 1];
                float cC2 = s4.z + tvC[i + 2], cC3 = s4.w + tvC[i + 3];
                bC = fmaxf(fmaxf(bC, cC0), cC1); bC = fmaxf(fmaxf(bC, cC2), cC3);
                float cD0 = s4.x + tvD[i],     cD1 = s4.y + tvD[i + 1];
                float cD2 = s4.z + tvD[i + 2], cD3 = s4.w + tvD[i + 3];
                bD = fmaxf(fmaxf(bD, cD0), cD1); bD = fmaxf(fmaxf(bD, cD2), cD3);
            }
            *(float4*)(part + q * Tn + j0) = make_float4(bA, bB, bC, bD);
            __syncthreads();
            if (tid < Tn) {
                float bb = part[tid];
                #pragma unroll
                for (int q2 = 1; q2 < 8; ++q2) bb = fmaxf(bb, part[q2 * Tn + tid]);
                hist[((size_t)t * Bn + b) * Tn + tid] = bb;
                cur = bb + emit_cur;
                emit_cur = emit_next;
                sbuf[tid] = cur;
            }
            __syncthreads();
        }

        // epilogue: last = argmax_j(cur + end_t[j]), ties -> smallest j
        float bv = -INFINITY; int bj = 0;
        if (tid < Tn) { bv = cur + end_t[tid]; bj = tid; }
        #pragma unroll
        for (int off = 32; off; off >>= 1) {
            float ov = __shfl_xor(bv, off);
            int   oj = __shfl_xor(bj, off);
            if (ov > bv || (ov == bv && oj < bj)) { bv = ov; bj = oj; }
        }
        if (lane == 0) { wredf[wv] = bv; wredi[wv] = bj; }
        __syncthreads();
        if (tid == 0) {
            float BB = wredf[0]; int AA = wredi[0];
            #pragma unroll
            for (int w = 1; w < 4; ++w)
                if (wredf[w] > BB || (wredf[w] == BB && wredi[w] < AA)) { BB = wredf[w]; AA = wredi[w]; }
            last_out[b] = AA;
        }
    } else {
        // ---- register-resident exp(trans) as packed f16 row-pairs: 4 cols x 16 pairs ----
        vu16t tdA, tdB, tdC, tdD;
        #pragma unroll
        for (int k = 0; k < 16; ++k) {
            uint4 v = *(const uint4*)(E16w + (size_t)(16 * q + k) * Tn + j0);
            tdA[k] = v.x; tdB[k] = v.y; tdC[k] = v.z; tdD[k] = v.w;
        }

        const float SHIFT = 9.0f;
        float pbase = 0.0f;
        if (tid < Tn) {
            cur = start_t[tid] + lg[0];
            if (tid == 0) msh[0] = cur;
            emit_cur = lg[Tn];
        }
        __syncthreads();
        if (tid < Tn) {
            pbase = msh[0] + SHIFT;
            p16[tid] = (_Float16)__expf(cur - pbase);
        }
        __syncthreads();

        for (int t = 1; t < len; ++t) {
            if (tid < Tn) {
                int tn = (t + 1 < len) ? (t + 1) : (len - 1);
                emit_next = lg[(size_t)tn * Tn];
            }
            // phase 1: partial dot(p16, E16) over my 32 rows for my 4 cols
            float sA = 0.f, sB = 0.f, sC = 0.f, sD = 0.f;
            #pragma unroll
            for (int k = 0; k < 8; ++k) {
                uint2 pp = *(const uint2*)(p16w + q * 16 + 2 * k);
                int i = 2 * k;
                sA = dot2h(pp.x, tdA[i], sA); sA = dot2h(pp.y, tdA[i + 1], sA);
                sB = dot2h(pp.x, tdB[i], sB); sB = dot2h(pp.y, tdB[i + 1], sB);
                sC = dot2h(pp.x, tdC[i], sC); sC = dot2h(pp.y, tdC[i + 1], sC);
                sD = dot2h(pp.x, tdD[i], sD); sD = dot2h(pp.y, tdD[i + 1], sD);
            }
            *(float4*)(part + q * Tn + j0) = make_float4(sA, sB, sC, sD);
            __syncthreads();
            // phase 2: combine, log, re-exponentiate with lag-1 shifted base
            if (tid < Tn) {
                float tot = part[tid];
                #pragma unroll
                for (int q2 = 1; q2 < 8; ++q2) tot += part[q2 * Tn + tid];
                float nb = msh[(t - 1) & 1];           // cur_0 from step t-1
                cur = pbase + __logf(tot) + emit_cur;
                emit_cur = emit_next;
                p16[tid] = (_Float16)__expf(cur - nb - SHIFT);
                pbase = nb + SHIFT;
                if (tid == 0) msh[t & 1] = cur;
            }
            __syncthreads();
        }

        // epilogue: den = logsumexp_j(cur + end_t[j]) (exact fp32)
        float v2 = (tid < Tn) ? (cur + end_t[tid]) : -INFINITY;
        float wm = v2;
        #pragma unroll
        for (int off = 32; off; off >>= 1) wm = fmaxf(wm, __shfl_xor(wm, off));
        if (lane == 0) wredf[wv] = wm;
        __syncthreads();
        float M = fmaxf(fmaxf(wredf[0], wredf[1]), fmaxf(wredf[2], wredf[3]));
        float ex = (tid < Tn) ? __expf(v2 - M) : 0.0f;
        #pragma unroll
        for (int off = 32; off; off >>= 1) ex += __shfl_xor(ex, off);
        if (lane == 0) wnum[wv] = ex;
        __syncthreads();
        if (tid == 0) den_out[b] = M + __logf(wnum[0] + wnum[1] + wnum[2] + wnum[3]);
        __syncthreads();

        // ---- numerator (fused; vit blocks are the wall) ----
        float acc = 0.0f;
        if (tid >= 1 && tid < len) {
            int prev = labels[b * Sn + tid - 1], curl = labels[b * Sn + tid];
            acc = trans[prev * Tn + curl] + logits[((size_t)b * Sn + tid) * Tn + curl];
        }
        #pragma unroll
        for (int off = 32; off; off >>= 1) acc += __shfl_xor(acc, off);
        if (lane == 0) wnum[wv] = acc;
        __syncthreads();
        if (tid == 0) {
            float s = 0.0f;
            #pragma unroll
            for (int w = 0; w < 8; ++w) s += wnum[w];
            int l0 = labels[b * Sn];
            int ll = labels[b * Sn + len - 1];
            num_out[b] = start_t[l0] + logits[(size_t)b * Sn * Tn + l0] + s + end_t[ll];
        }
    }
}

// ---------------- equality backtrack (blocks 0..127) + loss (block 128) ----------------
// Streaming prefetches use NT loads so transT stays L2-resident (its row load is
// the only dependent load on the serial chain).
__global__ void bt_loss_kernel(const float* __restrict__ hist,
                               const float* __restrict__ logits,
                               const float* __restrict__ start_t,
                               const float* __restrict__ transT,
                               const int* __restrict__ last,
                               const int* __restrict__ lengths,
                               const float* __restrict__ num,
                               const float* __restrict__ den,
                               float* __restrict__ pred,
                               float* __restrict__ out_loss) {
    const int lane = threadIdx.x;   // 64 threads
    if (blockIdx.x == Bn) {
        float v = (den[lane] - num[lane]) + (den[lane + 64] - num[lane + 64]);
        #pragma unroll
        for (int off = 32; off; off >>= 1) v += __shfl_xor(v, off);
        if (lane == 0) out_loss[0] = v * (1.0f / 128.0f);
        return;
    }
    const int b = blockIdx.x;
    const int len = lengths[b], len1 = len - 1;
    __shared__ int tg[Sn];
    int tag = last[b];
    if (lane == 0) tg[len1] = tag;
    float target = hist[((size_t)len1 * Bn + b) * Tn + tag];

    const float* lgrowf = logits + (size_t)b * Sn * Tn + lane * 4;   // + r*256
    const float* histbf = hist + (size_t)b * Tn + lane * 4;          // + rh*Bn*Tn
    float4 s4 = *((const float4*)start_t + lane);

    const int PF = 8;
    float4 hbuf[PF], ebuf[PF];
    #pragma unroll
    for (int u = 0; u < PF; ++u) {
        int r = len1 - 1 - u;
        if (r >= 0) {
            int rh = (r > 1) ? r : 1;
            ebuf[u] = nt_load4(lgrowf + (size_t)r * Tn);
            hbuf[u] = nt_load4(histbf + (size_t)rh * (Bn * Tn));
        }
    }

    // chunk-unrolled so hbuf/ebuf indices are compile-time constants (stay in VGPRs)
    for (int k0 = 0; k0 < len1; k0 += PF) {
        #pragma unroll
        for (int u = 0; u < PF; ++u) {
            int k = k0 + u;
            if (k < len1) {
                int r = len1 - 1 - k;               // previous-time row index
                // serial-critical load FIRST (L2-hot transT row)
                float4 t4 = *((const float4*)(transT + (size_t)tag * Tn) + lane);
                float4 h4 = hbuf[u], e4 = ebuf[u];
                int rp = r - PF;                    // prefetch PF steps ahead (NT)
                if (rp >= 0) {
                    int rh = (rp > 1) ? rp : 1;
                    ebuf[u] = nt_load4(lgrowf + (size_t)rp * Tn);
                    hbuf[u] = nt_load4(histbf + (size_t)rh * (Bn * Tn));
                }
                float4 sv;
                if (r > 0) {
                    sv.x = h4.x + e4.x; sv.y = h4.y + e4.y; sv.z = h4.z + e4.z; sv.w = h4.w + e4.w;
                } else {
                    sv.x = s4.x + e4.x; sv.y = s4.y + e4.y; sv.z = s4.z + e4.z; sv.w = s4.w + e4.w;
                }
                // 4 ballots (no LDS-shuffle on the tag critical path)
                unsigned long long B0 = __ballot((sv.x + t4.x) == target);
                unsigned long long B1 = __ballot((sv.y + t4.y) == target);
                unsigned long long B2 = __ballot((sv.z + t4.z) == target);
                unsigned long long B3 = __ballot((sv.w + t4.w) == target);
                int c0 = B0 ? ((__ffsll(B0) - 1) * 4 + 0) : 1024;
                int c1 = B1 ? ((__ffsll(B1) - 1) * 4 + 1) : 1024;
                int c2 = B2 ? ((__ffsll(B2) - 1) * 4 + 2) : 1024;
                int c3 = B3 ? ((__ffsll(B3) - 1) * 4 + 3) : 1024;
                tag = min(min(c0, c1), min(c2, c3));
                if (lane == 0) tg[r] = tag;
                int L = tag >> 2, slot = tag & 3;
                float hv = (slot == 0) ? h4.x : (slot == 1) ? h4.y : (slot == 2) ? h4.z : h4.w;
                target = __shfl(hv, L);              // hist[r][tag]; overlaps next t4 load
            }
        }
    }
    __syncthreads();
    for (int t = lane; t < Sn; t += 64)
        pred[(size_t)b * Sn + t] = (t < len) ? (float)tg[t] : 0.0f;
}

// ===================================================================
// FALLBACK PATH (round-1, proven): used only if ws_size is too small
// ===================================================================

__global__ void compute_E_kernel(const float* __restrict__ trans, __hip_bfloat16* __restrict__ E) {
    int k = blockIdx.x * blockDim.x + threadIdx.x;
    if (k < Tn * Tn) E[k] = __float2bfloat16(__expf(trans[k]));
}

__global__ void lengths_kernel(const void* __restrict__ mask, int* __restrict__ lengths) {
    int b = blockIdx.x, tid = threadIdx.x;
    const unsigned int* mu = (const unsigned int*)mask;
    unsigned int w0 = mu[0];
    int cnt = 0;
    if (w0 == 1u) {
        const int* mi = (const int*)mask;
        for (int t = tid; t < Sn; t += 256) cnt += (mi[b * Sn + t] != 0);
    } else if (w0 == 0x3F800000u) {
        const float* mf = (const float*)mask;
        for (int t = tid; t < Sn; t += 256) cnt += (mf[b * Sn + t] != 0.0f);
    } else {
        const unsigned char* mb = (const unsigned char*)mask;
        for (int t = tid; t < Sn; t += 256) cnt += (mb[b * Sn + t] != 0);
    }
    for (int off = 32; off; off >>= 1) cnt += __shfl_xor(cnt, off);
    __shared__ int red[4];
    if ((tid & 63) == 0) red[tid >> 6] = cnt;
    __syncthreads();
    if (tid == 0) lengths[b] = red[0] + red[1] + red[2] + red[3];
}

__global__ void numerator_kernel(const float* __restrict__ logits, const int* __restrict__ labels,
                                 const float* __restrict__ start_t, const float* __restrict__ end_t,
                                 const float* __restrict__ trans, const int* __restrict__ lengths,
                                 float* __restrict__ num) {
    int b = blockIdx.x, tid = threadIdx.x;
    int len = lengths[b];
    float acc = 0.0f;
    for (int t = tid + 1; t < len; t += 256) {
        int prev = labels[b * Sn + t - 1], cur = labels[b * Sn + t];
        acc += trans[prev * Tn + cur] + logits[((size_t)b * Sn + t) * Tn + cur];
    }
    for (int off = 32; off; off >>= 1) acc += __shfl_xor(acc, off);
    __shared__ float red[4];
    if ((tid & 63) == 0) red[tid >> 6] = acc;
    __syncthreads();
    if (tid == 0) {
        int l0 = labels[b * Sn];
        int ll = labels[b * Sn + len - 1];
        num[b] = start_t[l0] + logits[(size_t)b * Sn * Tn + l0]
               + red[0] + red[1] + red[2] + red[3] + end_t[ll];
    }
}

__launch_bounds__(1024)
__global__ void fused_fwd_kernel(const float* __restrict__ logits,
                                 const float* __restrict__ start_t,
                                 const float* __restrict__ end_t,
                                 const float* __restrict__ trans,
                                 const __hip_bfloat16* __restrict__ E,
                                 const int* __restrict__ lengths,
                                 unsigned char* __restrict__ hist,
                                 float* __restrict__ den_out,
                                 int* __restrict__ last_out) {
    int b = blockIdx.x;
    int tid = threadIdx.x;
    int j = tid & 255;
    int h = tid >> 8;
    int i0 = h * 64;

    __shared__ __align__(16) float sden[Tn];
    __shared__ __align__(16) float svit[Tn];
    __shared__ __align__(16) float p[Tn];
    __shared__ float redf[16];
    __shared__ float reds[16];
    __shared__ float redb[16];
    __shared__ int   redbi[16];
    __shared__ float pd[1024];
    __shared__ float pv[1024];
    __shared__ int   pa[1024];

    int len = lengths[b];
    if (tid < Tn) {
        float v = start_t[j] + logits[(size_t)b * Sn * Tn + j];
        sden[j] = v;
        svit[j] = v;
    }
    __syncthreads();

    for (int t = 1; t < len; ++t) {
        float v = sden[j];
        for (int off = 32; off; off >>= 1) v = fmaxf(v, __shfl_xor(v, off));
        if ((tid & 63) == 0) redf[tid >> 6] = v;
        __syncthreads();
        float m = redf[0];
        #pragma unroll
        for (int w = 1; w < 16; ++w) m = fmaxf(m, redf[w]);
        if (tid < Tn) p[j] = __expf(sden[j] - m);
        __syncthreads();

        float s = 0.0f, best = -INFINITY;
        int arg = 0;
        const float* tr = trans + (size_t)i0 * Tn + j;
        const __hip_bfloat16* er = E + (size_t)i0 * Tn + j;
        #pragma unroll 4
        for (int i = i0; i < i0 + 64; i += 4) {
            float4 p4  = *(const float4*)(p + i);
            float4 sv4 = *(const float4*)(svit + i);
            float tr0 = tr[0 * Tn], tr1 = tr[1 * Tn], tr2 = tr[2 * Tn], tr3 = tr[3 * Tn];
            float e0 = __bfloat162float(er[0 * Tn]);
            float e1 = __bfloat162float(er[1 * Tn]);
            float e2 = __bfloat162float(er[2 * Tn]);
            float e3 = __bfloat162float(er[3 * Tn]);
            tr += 4 * Tn; er += 4 * Tn;
            s = fmaf(p4.x, e0, s); s = fmaf(p4.y, e1, s);
            s = fmaf(p4.z, e2, s); s = fmaf(p4.w, e3, s);
            float c0 = sv4.x + tr0; if (c0 > best) { best = c0; arg = i + 0; }
            float c1 = sv4.y + tr1; if (c1 > best) { best = c1; arg = i + 1; }
            float c2 = sv4.z + tr2; if (c2 > best) { best = c2; arg = i + 2; }
            float c3 = sv4.w + tr3; if (c3 > best) { best = c3; arg = i + 3; }
        }
        pd[tid] = s; pv[tid] = best; pa[tid] = arg;
        __syncthreads();

        if (tid < Tn) {
            float ss = pd[j] + pd[j + 256] + pd[j + 512] + pd[j + 768];
            float bb = pv[j]; int aa = pa[j];
            if (pv[j + 256] > bb) { bb = pv[j + 256]; aa = pa[j + 256]; }
            if (pv[j + 512] > bb) { bb = pv[j + 512]; aa = pa[j + 512]; }
            if (pv[j + 768] > bb) { bb = pv[j + 768]; aa = pa[j + 768]; }
            float emit = logits[((size_t)b * Sn + t) * Tn + j];
            sden[j] = m + __logf(ss) + emit;
            svit[j] = bb + emit;
            hist[((size_t)t * Bn + b) * Tn + j] = (unsigned char)aa;
        }
        __syncthreads();
    }

    float v2d = sden[j] + end_t[j];
    float M = v2d;
    for (int off = 32; off; off >>= 1) M = fmaxf(M, __shfl_xor(M, off));
    if ((tid & 63) == 0) redf[tid >> 6] = M;
    __syncthreads();
    M = redf[0];
    #pragma unroll
    for (int w = 1; w < 16; ++w) M = fmaxf(M, redf[w]);

    float ex = (tid < Tn) ? __expf(v2d - M) : 0.0f;
    for (int off = 32; off; off >>= 1) ex += __shfl_xor(ex, off);

    float v2v = svit[j] + end_t[j];
    float bv = v2v; int bj = j;
    for (int off = 32; off; off >>= 1) {
        float ov = __shfl_xor(bv, off); int oj = __shfl_xor(bj, off);
        if (ov > bv || (ov == bv && oj < bj)) { bv = ov; bj = oj; }
    }
    if ((tid & 63) == 0) { reds[tid >> 6] = ex; redb[tid >> 6] = bv; redbi[tid >> 6] = bj; }
    __syncthreads();
    if (tid == 0) {
        float sum = 0.0f;
        #pragma unroll
        for (int w = 0; w < 16; ++w) sum += reds[w];
        den_out[b] = M + __logf(sum);
        float BB = redb[0]; int AA = redbi[0];
        #pragma unroll
        for (int w = 1; w < 16; ++w)
            if (redb[w] > BB || (redb[w] == BB && redbi[w] < AA)) { BB = redb[w]; AA = redbi[w]; }
        last_out[b] = AA;
    }
}

__global__ void backtrack_kernel(const unsigned char* __restrict__ hist,
                                 const int* __restrict__ last,
                                 const int* __restrict__ lengths,
                                 float* __restrict__ pred) {
    int b = blockIdx.x, lane = threadIdx.x;
    int len = lengths[b];
    int len1 = len - 1;
    __shared__ int tg[Sn];
    int tag = last[b];

    if (lane == 0) tg[len1] = tag;
    for (int qq = 0; qq < len1; ++qq) {
        int r = len1 - qq;
        unsigned int w = *(const unsigned int*)(hist + ((size_t)r * Bn + b) * Tn + lane * 4);
        int sel = __shfl((int)w, tag >> 2, 64);
        tag = (sel >> ((tag & 3) * 8)) & 255;
        if (lane == 0) tg[r - 1] = tag;
    }
    __syncthreads();
    for (int t = lane; t < Sn; t += 64)
        pred[(size_t)b * Sn + t] = (t < len) ? (float)tg[t] : 0.0f;
}

__global__ void loss_kernel(const float* __restrict__ num, const float* __restrict__ den,
                            float* __restrict__ out_loss) {
    int tid = threadIdx.x;
    float v = den[tid] - num[tid];
    for (int off = 32; off; off >>= 1) v += __shfl_xor(v, off);
    __shared__ float r2[2];
    if ((tid & 63) == 0) r2[tid >> 6] = v;
    __syncthreads();
    if (tid == 0) out_loss[0] = (r2[0] + r2[1]) * (1.0f / 128.0f);
}

// ===================================================================

extern "C" void kernel_launch(void* const* d_in, const int* in_sizes, int n_in,
                              void* d_out, int out_size, void* d_ws, size_t ws_size,
                              hipStream_t stream) {
    const float* logits  = (const float*)d_in[0];
    const void*  mask    = d_in[1];
    const int*   labels  = (const int*)d_in[2];
    const float* start_t = (const float*)d_in[3];
    const float* end_t   = (const float*)d_in[4];
    const float* trans   = (const float*)d_in[5];
    float* out = (float*)d_out;   // [B*S] pred as float, then [1] loss

    char* ws = (char*)d_ws;
    const size_t histF = (size_t)Sn * Bn * Tn * 4;           // 67.1 MB fp32 best-value hist
    const size_t tblF  = (size_t)Tn * Tn * 4;                // 256 KB
    const size_t e16F  = (size_t)Tn * Tn * 2;                // 128 KB
    const size_t needF = histF + tblF + e16F + 8192;

    if (ws_size >= needF) {
        // -------- fast path --------
        float*        hist    = (float*)ws;
        float*        transT  = (float*)(ws + histF);
        _Float16*     E16     = (_Float16*)(ws + histF + tblF);
        char*         tail    = ws + histF + tblF + e16F;
        int*          lengths = (int*)tail;
        float*        num     = (float*)(tail + 2048);
        float*        den     = (float*)(tail + 4096);
        int*          lastp   = (int*)(tail + 6144);

        prep_kernel<<<Tn * Tn / 256, 256, 0, stream>>>(trans, transT, E16);
        crf_fwd3_kernel<<<2 * Bn, 512, 0, stream>>>(logits, start_t, end_t, trans,
                                                    (const unsigned int*)E16, mask,
                                                    labels, lengths, hist, den, lastp, num);
        bt_loss_kernel<<<Bn + 1, 64, 0, stream>>>(hist, logits, start_t, transT, lastp,
                                                  lengths, num, den, out, out + (size_t)Bn * Sn);
    } else {
        // -------- fallback: proven round-1 path (~17 MB ws) --------
        const size_t histSz = (size_t)Sn * Bn * Tn;
        unsigned char*  hist    = (unsigned char*)ws;
        int*            lengths = (int*)(ws + histSz);
        float*          num     = (float*)(ws + histSz + 512);
        float*          den     = (float*)(ws + histSz + 1024);
        int*            lastp   = (int*)(ws + histSz + 1536);
        __hip_bfloat16* E       = (__hip_bfloat16*)(ws + histSz + 2048);

        compute_E_kernel<<<(Tn * Tn) / 256, 256, 0, stream>>>(trans, E);
        lengths_kernel<<<Bn, 256, 0, stream>>>(mask, lengths);
        fused_fwd_kernel<<<Bn, 1024, 0, stream>>>(logits, start_t, end_t, trans, E,
                                                  lengths, hist, den, lastp);
        numerator_kernel<<<Bn, 256, 0, stream>>>(logits, labels, start_t, end_t, trans,
                                                 lengths, num);
        backtrack_kernel<<<Bn, 64, 0, stream>>>(hist, lastp, lengths, out);
        loss_kernel<<<1, 128, 0, stream>>>(num, den, out + (size_t)Bn * Sn);
    }
}